// Round 1
// baseline (2055.260 us; speedup 1.0000x reference)
//
#include <hip/hip_runtime.h>
#include <hip/hip_bf16.h>

// Problem constants (verified against setup_inputs at runtime via in_sizes)
// H=2, C=64, IN=128, EIN=64, N=50000, E=800000

__device__ __forceinline__ float lrelu(float v) { return v >= 0.f ? v : 0.2f * v; }

// ---------------- CSR build ----------------
__global__ void count_kernel(const int* __restrict__ dst, int* __restrict__ cnt, int E) {
    int e = blockIdx.x * blockDim.x + threadIdx.x;
    if (e < E) atomicAdd(&cnt[dst[e]], 1);
}

__global__ __launch_bounds__(1024) void scan_kernel(const int* __restrict__ cnt, int* __restrict__ rowptr, int n) {
    __shared__ int part[1024];
    int t = threadIdx.x;
    int CH = (n + 1023) / 1024;
    int base = t * CH;
    int local = 0;
    for (int i = 0; i < CH; i++) { int idx = base + i; if (idx < n) local += cnt[idx]; }
    part[t] = local;
    __syncthreads();
    for (int o = 1; o < 1024; o <<= 1) {
        int v = (t >= o) ? part[t - o] : 0;
        __syncthreads();
        part[t] += v;
        __syncthreads();
    }
    int run = part[t] - local;  // exclusive prefix
    for (int i = 0; i < CH; i++) {
        int idx = base + i;
        if (idx < n) { rowptr[idx] = run; run += cnt[idx]; }
    }
    if (t == 1023) rowptr[n] = run;  // total == E
}

__global__ void scatter_kernel(const int* __restrict__ src, const int* __restrict__ dst,
                               int* __restrict__ cursor, int* __restrict__ ssrc, int E) {
    int e = blockIdx.x * blockDim.x + threadIdx.x;
    if (e < E) {
        int pos = atomicAdd(&cursor[dst[e]], 1);
        ssrc[pos] = src[e];
    }
}

// ---------------- per-row GEMM helper: acc[0..127] = xr[0..K-1] @ W[K,128] ----------------
template <int K>
__device__ __forceinline__ void row_gemm_128(const float* __restrict__ xr,
                                             const float* __restrict__ W,
                                             float acc[128]) {
#pragma unroll
    for (int j = 0; j < 128; j++) acc[j] = 0.f;
    for (int kc = 0; kc < K; kc += 16) {
        float xv[16];
#pragma unroll
        for (int i = 0; i < 16; i += 4) {
            float4 t = *(const float4*)(xr + kc + i);
            xv[i] = t.x; xv[i + 1] = t.y; xv[i + 2] = t.z; xv[i + 3] = t.w;
        }
#pragma unroll
        for (int k = 0; k < 16; k++) {
            const float* __restrict__ wrow = W + (size_t)(kc + k) * 128;
#pragma unroll
            for (int j = 0; j < 128; j++) acc[j] = fmaf(xv[k], wrow[j], acc[j]);
        }
    }
}

// ---------------- encoder GEMM: xw = X@W, plus attention dots a_s, a_d ----------------
template <int K>
__global__ __launch_bounds__(256) void enc_gemm(const float* __restrict__ X, const float* __restrict__ W,
                                                const float* __restrict__ avs, const float* __restrict__ avd,
                                                float* __restrict__ xw, float* __restrict__ a_s,
                                                float* __restrict__ a_d, int Nn) {
    int n = blockIdx.x * blockDim.x + threadIdx.x;
    if (n >= Nn) return;
    float acc[128];
    row_gemm_128<K>(X + (size_t)n * K, W, acc);
    float as0 = 0.f, as1 = 0.f, ad0 = 0.f, ad1 = 0.f;
#pragma unroll
    for (int j = 0; j < 64; j++) { as0 = fmaf(acc[j], avs[j], as0); ad0 = fmaf(acc[j], avd[j], ad0); }
#pragma unroll
    for (int j = 64; j < 128; j++) { as1 = fmaf(acc[j], avs[j], as1); ad1 = fmaf(acc[j], avd[j], ad1); }
    float* xwr = xw + (size_t)n * 128;
#pragma unroll
    for (int j = 0; j < 128; j += 4) {
        float4 t = {acc[j], acc[j + 1], acc[j + 2], acc[j + 3]};
        *(float4*)(xwr + j) = t;
    }
    a_s[n * 2] = as0; a_s[n * 2 + 1] = as1;
    a_d[n * 2] = ad0; a_d[n * 2 + 1] = ad1;
}

// ---------------- fused tail: rows >= N have only their self-loop (alpha==1) ----------------
__global__ __launch_bounds__(256) void edge_tail_kernel(const float* __restrict__ xe, const float* __restrict__ We,
                                                        const float* __restrict__ be, const float* __restrict__ Wde,
                                                        const float* __restrict__ bde, float* __restrict__ e_rec,
                                                        int N, int NE) {
    int row = N + blockIdx.x * blockDim.x + threadIdx.x;
    if (row >= NE) return;
    float acc[128];
    row_gemm_128<64>(xe + (size_t)row * 64, We, acc);
    float h[64];
#pragma unroll
    for (int c = 0; c < 64; c++) h[c] = fmaf(0.5f, acc[c] + acc[64 + c], be[c]);
    float er[64];
#pragma unroll
    for (int j = 0; j < 64; j++) er[j] = bde[j];
#pragma unroll
    for (int c = 0; c < 64; c++) {
        float hv = h[c];
        const float* __restrict__ wr = Wde + c * 64;
#pragma unroll
        for (int j = 0; j < 64; j++) er[j] = fmaf(hv, wr[j], er[j]);
    }
    float* o = e_rec + (size_t)row * 64;
#pragma unroll
    for (int j = 0; j < 64; j += 4) {
        float4 t = {er[j], er[j + 1], er[j + 2], er[j + 3]};
        *(float4*)(o + j) = t;
    }
}

// ---------------- segment softmax + aggregate + head-mean + decoder, one block per dst node ----
__global__ __launch_bounds__(128) void msg_decode(const float* __restrict__ xw, const float* __restrict__ a_s,
                                                  const float* __restrict__ a_d, const int* __restrict__ rowptr,
                                                  const int* __restrict__ ssrc, const float* __restrict__ bconv,
                                                  const float* __restrict__ Wdec, const float* __restrict__ bdec,
                                                  float* __restrict__ out, int outD) {
    int n = blockIdx.x;
    int tid = threadIdx.x;
    int h = tid >> 6, c = tid & 63;
    __shared__ float hsh[128];
    __shared__ float hm[64];

    int base = rowptr[n];
    int deg = rowptr[n + 1] - base;
    float adh = a_d[n * 2 + h];
    float es = lrelu(a_s[n * 2 + h] + adh);

    // 1) segment max (lanes parallel over incoming edges, wave = one head)
    float mx = -1e30f;
    for (int i = c; i < deg; i += 64) {
        int s = ssrc[base + i];
        mx = fmaxf(mx, lrelu(a_s[s * 2 + h] + adh));
    }
#pragma unroll
    for (int o = 1; o < 64; o <<= 1) mx = fmaxf(mx, __shfl_xor(mx, o));
    mx = fmaxf(mx, es);

    // 2) denominator
    float den = 0.f;
    for (int i = c; i < deg; i += 64) {
        int s = ssrc[base + i];
        den += expf(lrelu(a_s[s * 2 + h] + adh) - mx);
    }
#pragma unroll
    for (int o = 1; o < 64; o <<= 1) den += __shfl_xor(den, o);
    float wself = expf(es - mx);
    den += wself;

    // 3) weighted aggregation (lane c = channel, sequential over edges)
    float acc = wself * xw[(size_t)n * 128 + h * 64 + c];
    for (int i = 0; i < deg; i++) {
        int s = ssrc[base + i];
        float w = expf(lrelu(a_s[s * 2 + h] + adh) - mx);
        acc = fmaf(w, xw[(size_t)s * 128 + h * 64 + c], acc);
    }
    hsh[tid] = acc / den;
    __syncthreads();
    if (tid < 64) hm[tid] = fmaf(0.5f, hsh[tid] + hsh[64 + tid], bconv[tid]);
    __syncthreads();

    // 4) decoder row: out[n, :] = hm @ Wdec + bdec
    for (int j = tid; j < outD; j += 128) {
        float v = bdec[j];
        for (int cc = 0; cc < 64; cc++) v = fmaf(hm[cc], Wdec[cc * outD + j], v);
        out[(size_t)n * outD + j] = v;
    }
}

extern "C" void kernel_launch(void* const* d_in, const int* in_sizes, int n_in,
                              void* d_out, int out_size, void* d_ws, size_t ws_size,
                              hipStream_t stream) {
    const float* x   = (const float*)d_in[0];
    const float* xe  = (const float*)d_in[1];
    const int*   ei  = (const int*)d_in[2];
    const float* Wn  = (const float*)d_in[3];
    const float* asn = (const float*)d_in[4];
    const float* adn = (const float*)d_in[5];
    const float* bn  = (const float*)d_in[6];
    const float* We  = (const float*)d_in[7];
    const float* ase = (const float*)d_in[8];
    const float* ade = (const float*)d_in[9];
    const float* be  = (const float*)d_in[10];
    const float* Wdx = (const float*)d_in[11];
    const float* bdx = (const float*)d_in[12];
    const float* Wde = (const float*)d_in[13];
    const float* bde = (const float*)d_in[14];

    const int N  = in_sizes[0] / 128;  // 50000 nodes
    const int NE = in_sizes[1] / 64;   // 800000 edge-rows
    const int E  = in_sizes[2] / 2;    // 800000 edges
    const int* src = ei;
    const int* dst = ei + E;

    char* wsb = (char*)d_ws;
    size_t off = 0;
    auto alloc = [&](size_t bytes) -> void* {
        void* p = wsb + off;
        off += (bytes + 255) & ~(size_t)255;
        return p;
    };
    float* xw_n = (float*)alloc((size_t)N * 128 * 4);
    float* a_sn = (float*)alloc((size_t)N * 2 * 4);
    float* a_dn = (float*)alloc((size_t)N * 2 * 4);
    float* xw_e = (float*)alloc((size_t)N * 128 * 4);
    float* a_se = (float*)alloc((size_t)N * 2 * 4);
    float* a_de = (float*)alloc((size_t)N * 2 * 4);
    int* cnt    = (int*)alloc((size_t)(N + 1) * 4);
    int* rowptr = (int*)alloc((size_t)(N + 1) * 4);
    int* cursor = (int*)alloc((size_t)(N + 1) * 4);
    int* ssrc   = (int*)alloc((size_t)E * 4);

    float* x_rec = (float*)d_out;
    float* e_rec = (float*)d_out + (size_t)N * 128;

    // CSR build (shared by both convs — identical edge structure)
    hipMemsetAsync(cnt, 0, (size_t)N * 4, stream);
    count_kernel<<<(E + 255) / 256, 256, 0, stream>>>(dst, cnt, E);
    scan_kernel<<<1, 1024, 0, stream>>>(cnt, rowptr, N);
    hipMemcpyAsync(cursor, rowptr, (size_t)N * 4, hipMemcpyDeviceToDevice, stream);
    scatter_kernel<<<(E + 255) / 256, 256, 0, stream>>>(src, dst, cursor, ssrc, E);

    // Encoders
    enc_gemm<128><<<(N + 255) / 256, 256, 0, stream>>>(x, Wn, asn, adn, xw_n, a_sn, a_dn, N);
    enc_gemm<64><<<(N + 255) / 256, 256, 0, stream>>>(xe, We, ase, ade, xw_e, a_se, a_de, N);

    // 750k self-loop-only rows: fully fused encode->mean->decode
    edge_tail_kernel<<<(NE - N + 255) / 256, 256, 0, stream>>>(xe, We, be, Wde, bde, e_rec, N, NE);

    // Softmax aggregation + decode for the 50k "real" destination segments
    msg_decode<<<N, 128, 0, stream>>>(xw_n, a_sn, a_dn, rowptr, ssrc, bn, Wdx, bdx, x_rec, 128);
    msg_decode<<<N, 128, 0, stream>>>(xw_e, a_se, a_de, rowptr, ssrc, be, Wde, bde, e_rec, 64);
}

// Round 3
// 971.001 us; speedup vs baseline: 2.1166x; 2.1166x over previous
//
#include <hip/hip_runtime.h>
#include <hip/hip_bf16.h>

// H=2, C=64, IN=128, EIN=64, N=50000, E=800000
constexpr int MAXD = 512;

__device__ __forceinline__ float lrelu(float v) { return v >= 0.f ? v : 0.2f * v; }

// ---------------- CSR build ----------------
__global__ void count_kernel(const int* __restrict__ dst, int* __restrict__ cnt, int E) {
    int e = blockIdx.x * blockDim.x + threadIdx.x;
    if (e < E) atomicAdd(&cnt[dst[e]], 1);
}

__global__ __launch_bounds__(1024) void scan_kernel(const int* __restrict__ cnt, int* __restrict__ rowptr, int n) {
    __shared__ int part[1024];
    int t = threadIdx.x;
    int CH = (n + 1023) / 1024;
    int base = t * CH;
    int local = 0;
    for (int i = 0; i < CH; i++) { int idx = base + i; if (idx < n) local += cnt[idx]; }
    part[t] = local;
    __syncthreads();
    for (int o = 1; o < 1024; o <<= 1) {
        int v = (t >= o) ? part[t - o] : 0;
        __syncthreads();
        part[t] += v;
        __syncthreads();
    }
    int run = part[t] - local;  // exclusive prefix
    for (int i = 0; i < CH; i++) {
        int idx = base + i;
        if (idx < n) { rowptr[idx] = run; run += cnt[idx]; }
    }
    if (t == 1023) rowptr[n] = run;
}

__global__ void scatter_kernel(const int* __restrict__ src, const int* __restrict__ dst,
                               int* __restrict__ cursor, int* __restrict__ ssrc, int E) {
    int e = blockIdx.x * blockDim.x + threadIdx.x;
    if (e < E) {
        int pos = atomicAdd(&cursor[dst[e]], 1);
        ssrc[pos] = src[e];
    }
}

// ---------------- fold: M = We_fold @ Wde, b0 = be@Wde + bde ----------------
__global__ void fold_kernel(const float* __restrict__ We, const float* __restrict__ Wde,
                            const float* __restrict__ be, const float* __restrict__ bde,
                            float* __restrict__ M, float* __restrict__ b0) {
    int j = threadIdx.x;  // 0..63
    int k = blockIdx.x;   // 0..64; block 64 does b0
    if (k < 64) {
        float s = 0.f;
        for (int c = 0; c < 64; c++)
            s = fmaf(0.5f * (We[k * 128 + c] + We[k * 128 + 64 + c]), Wde[c * 64 + j], s);
        M[k * 64 + j] = s;
    } else {
        float s = bde[j];
        for (int c = 0; c < 64; c++) s = fmaf(be[c], Wde[c * 64 + j], s);
        b0[j] = s;
    }
}

// ---------------- encoder: one head per thread (h = blockIdx.y) ----------------
template <int K>
__global__ __launch_bounds__(256) void enc_gemm(const float* __restrict__ X, const float* __restrict__ W,
                                                const float* __restrict__ avs, const float* __restrict__ avd,
                                                float* __restrict__ xw, float* __restrict__ a_s,
                                                float* __restrict__ a_d, int Nn) {
    int n = blockIdx.x * 256 + threadIdx.x;
    int h = blockIdx.y;
    if (n >= Nn) return;
    const float* xr = X + (size_t)n * K;
    float acc[64];
#pragma unroll
    for (int j = 0; j < 64; j++) acc[j] = 0.f;
    for (int kc = 0; kc < K; kc += 16) {
        float xv[16];
#pragma unroll
        for (int i = 0; i < 16; i += 4) {
            float4 t = *(const float4*)(xr + kc + i);
            xv[i] = t.x; xv[i + 1] = t.y; xv[i + 2] = t.z; xv[i + 3] = t.w;
        }
#pragma unroll
        for (int k = 0; k < 16; k++) {
            const float* wr = W + (size_t)(kc + k) * 128 + h * 64;
#pragma unroll
            for (int j = 0; j < 64; j++) acc[j] = fmaf(xv[k], wr[j], acc[j]);
        }
    }
    float as = 0.f, ad = 0.f;
    const float* vs = avs + h * 64;
    const float* vd = avd + h * 64;
#pragma unroll
    for (int j = 0; j < 64; j++) { as = fmaf(acc[j], vs[j], as); ad = fmaf(acc[j], vd[j], ad); }
    float* xwr = xw + (size_t)n * 128 + h * 64;
#pragma unroll
    for (int j = 0; j < 64; j += 4) {
        float4 t = {acc[j], acc[j + 1], acc[j + 2], acc[j + 3]};
        *(float4*)(xwr + j) = t;
    }
    a_s[n * 2 + h] = as;
    a_d[n * 2 + h] = ad;
}

// ---------------- row-map: out[r,:] = A[r,:] @ M + b0   (A is [R,64], M is [64,OD]) ----------
template <int OD>
__global__ __launch_bounds__(256) void rowmap_kernel(const float* __restrict__ A, const float* __restrict__ M,
                                                     const float* __restrict__ b0, float* __restrict__ out, int R) {
    int r = blockIdx.x * 256 + threadIdx.x;
    if (r >= R) return;
    const float* ar = A + (size_t)r * 64;
    float* orow = out + (size_t)r * OD;
    for (int jc = 0; jc < OD; jc += 64) {
        float acc[64];
#pragma unroll
        for (int j = 0; j < 64; j++) acc[j] = b0[jc + j];
        for (int kc = 0; kc < 64; kc += 16) {
            float xv[16];
#pragma unroll
            for (int i = 0; i < 16; i += 4) {
                float4 t = *(const float4*)(ar + kc + i);
                xv[i] = t.x; xv[i + 1] = t.y; xv[i + 2] = t.z; xv[i + 3] = t.w;
            }
#pragma unroll
            for (int k = 0; k < 16; k++) {
                const float* mr = M + (size_t)(kc + k) * OD + jc;
#pragma unroll
                for (int j = 0; j < 64; j++) acc[j] = fmaf(xv[k], mr[j], acc[j]);
            }
        }
#pragma unroll
        for (int j = 0; j < 64; j += 4) {
            float4 t = {acc[j], acc[j + 1], acc[j + 2], acc[j + 3]};
            *(float4*)(orow + jc + j) = t;
        }
    }
}

// ---------------- fused message passing for BOTH convs; outputs head-mean hm ----------------
__global__ __launch_bounds__(128) void msg_fused(
    const float* __restrict__ xw_n, const float* __restrict__ a_sn, const float* __restrict__ a_dn,
    const float* __restrict__ xw_e, const float* __restrict__ a_se, const float* __restrict__ a_de,
    const int* __restrict__ rowptr, const int* __restrict__ ssrc,
    const float* __restrict__ bn, const float* __restrict__ be,
    float* __restrict__ hm_n, float* __restrict__ hm_e) {
    int n = blockIdx.x;
    int tid = threadIdx.x;
    int h = tid >> 6, c = tid & 63;
    __shared__ int s_src[MAXD];
    __shared__ float t_n[2][MAXD];
    __shared__ float t_e[2][MAXD];
    __shared__ float red[8];  // [conv*4 + {m0,m1,d0,d1}]
    __shared__ float hsh[2][128];

    int base = rowptr[n];
    int deg = rowptr[n + 1] - base;
    int degc = min(deg, MAXD);

    float adn0 = a_dn[n * 2 + 0], adn1 = a_dn[n * 2 + 1];
    float ade0 = a_de[n * 2 + 0], ade1 = a_de[n * 2 + 1];
    float2 asn_n = *(const float2*)(a_sn + (size_t)n * 2);
    float2 ase_n = *(const float2*)(a_se + (size_t)n * 2);
    float es_n0 = lrelu(asn_n.x + adn0), es_n1 = lrelu(asn_n.y + adn1);
    float es_e0 = lrelu(ase_n.x + ade0), es_e1 = lrelu(ase_n.y + ade1);

    // pass 1: cache src indices + leaky-relu logits (ONE gather over a_s)
    for (int i = tid; i < degc; i += 128) {
        int s = ssrc[base + i];
        s_src[i] = s;
        float2 an = *(const float2*)(a_sn + (size_t)s * 2);
        float2 ae = *(const float2*)(a_se + (size_t)s * 2);
        t_n[0][i] = lrelu(an.x + adn0);
        t_n[1][i] = lrelu(an.y + adn1);
        t_e[0][i] = lrelu(ae.x + ade0);
        t_e[1][i] = lrelu(ae.y + ade1);
    }
    __syncthreads();

    // reductions: wave 0 -> conv n, wave 1 -> conv e (both heads per wave)
    int w = tid >> 6;
    int lane = tid & 63;
    {
        const float(*tt)[MAXD] = w ? t_e : t_n;
        const float* asx = w ? a_se : a_sn;
        float ad0 = w ? ade0 : adn0, ad1 = w ? ade1 : adn1;
        float es0 = w ? es_e0 : es_n0, es1 = w ? es_e1 : es_n1;
        float m0 = es0, m1 = es1;
        for (int i = lane; i < degc; i += 64) { m0 = fmaxf(m0, tt[0][i]); m1 = fmaxf(m1, tt[1][i]); }
        for (int i = MAXD + lane; i < deg; i += 64) {
            int s = ssrc[base + i];
            float2 a = *(const float2*)(asx + (size_t)s * 2);
            m0 = fmaxf(m0, lrelu(a.x + ad0)); m1 = fmaxf(m1, lrelu(a.y + ad1));
        }
#pragma unroll
        for (int o = 1; o < 64; o <<= 1) { m0 = fmaxf(m0, __shfl_xor(m0, o)); m1 = fmaxf(m1, __shfl_xor(m1, o)); }
        // denominator: edge terms reduced across lanes; self term added ONCE after reduction
        float d0 = 0.f, d1 = 0.f;
        for (int i = lane; i < degc; i += 64) { d0 += __expf(tt[0][i] - m0); d1 += __expf(tt[1][i] - m1); }
        for (int i = MAXD + lane; i < deg; i += 64) {
            int s = ssrc[base + i];
            float2 a = *(const float2*)(asx + (size_t)s * 2);
            d0 += __expf(lrelu(a.x + ad0) - m0); d1 += __expf(lrelu(a.y + ad1) - m1);
        }
#pragma unroll
        for (int o = 1; o < 64; o <<= 1) { d0 += __shfl_xor(d0, o); d1 += __shfl_xor(d1, o); }
        d0 += __expf(es0 - m0);  // self-loop contribution, exactly once
        d1 += __expf(es1 - m1);
        if (lane == 0) { red[w * 4 + 0] = m0; red[w * 4 + 1] = m1; red[w * 4 + 2] = d0; red[w * 4 + 3] = d1; }
    }
    __syncthreads();

    // convert logits -> unnormalized weights in LDS (once)
    for (int i = tid; i < degc; i += 128) {
        t_n[0][i] = __expf(t_n[0][i] - red[0]);
        t_n[1][i] = __expf(t_n[1][i] - red[1]);
        t_e[0][i] = __expf(t_e[0][i] - red[4]);
        t_e[1][i] = __expf(t_e[1][i] - red[5]);
    }
    __syncthreads();

    float mn = red[h], dn_ = red[2 + h];
    float me = red[4 + h], de_ = red[6 + h];
    float accn = __expf((h ? es_n1 : es_n0) - mn) * xw_n[(size_t)n * 128 + h * 64 + c];
    float acce = __expf((h ? es_e1 : es_e0) - me) * xw_e[(size_t)n * 128 + h * 64 + c];
    for (int i = 0; i < degc; i++) {
        int s = s_src[i];
        float wn_ = t_n[h][i];
        float we_ = t_e[h][i];
        accn = fmaf(wn_, xw_n[(size_t)s * 128 + h * 64 + c], accn);
        acce = fmaf(we_, xw_e[(size_t)s * 128 + h * 64 + c], acce);
    }
    for (int i = MAXD; i < deg; i++) {
        int s = ssrc[base + i];
        float2 an = *(const float2*)(a_sn + (size_t)s * 2);
        float2 ae = *(const float2*)(a_se + (size_t)s * 2);
        float tn_ = lrelu(h ? (an.y + adn1) : (an.x + adn0));
        float te_ = lrelu(h ? (ae.y + ade1) : (ae.x + ade0));
        accn = fmaf(__expf(tn_ - mn), xw_n[(size_t)s * 128 + h * 64 + c], accn);
        acce = fmaf(__expf(te_ - me), xw_e[(size_t)s * 128 + h * 64 + c], acce);
    }
    hsh[0][tid] = accn / dn_;
    hsh[1][tid] = acce / de_;
    __syncthreads();
    if (tid < 64) {
        hm_n[(size_t)n * 64 + tid] = fmaf(0.5f, hsh[0][tid] + hsh[0][64 + tid], bn[tid]);
        hm_e[(size_t)n * 64 + tid] = fmaf(0.5f, hsh[1][tid] + hsh[1][64 + tid], be[tid]);
    }
}

extern "C" void kernel_launch(void* const* d_in, const int* in_sizes, int n_in,
                              void* d_out, int out_size, void* d_ws, size_t ws_size,
                              hipStream_t stream) {
    const float* x   = (const float*)d_in[0];
    const float* xe  = (const float*)d_in[1];
    const int*   ei  = (const int*)d_in[2];
    const float* Wn  = (const float*)d_in[3];
    const float* asn = (const float*)d_in[4];
    const float* adn = (const float*)d_in[5];
    const float* bn  = (const float*)d_in[6];
    const float* We  = (const float*)d_in[7];
    const float* ase = (const float*)d_in[8];
    const float* ade = (const float*)d_in[9];
    const float* be  = (const float*)d_in[10];
    const float* Wdx = (const float*)d_in[11];
    const float* bdx = (const float*)d_in[12];
    const float* Wde = (const float*)d_in[13];
    const float* bde = (const float*)d_in[14];

    const int N  = in_sizes[0] / 128;  // 50000
    const int NE = in_sizes[1] / 64;   // 800000
    const int E  = in_sizes[2] / 2;    // 800000
    const int* src = ei;
    const int* dst = ei + E;

    char* wsb = (char*)d_ws;
    size_t off = 0;
    auto alloc = [&](size_t bytes) -> void* {
        void* p = wsb + off;
        off += (bytes + 255) & ~(size_t)255;
        return p;
    };
    float* xw_n = (float*)alloc((size_t)N * 128 * 4);
    float* a_sn = (float*)alloc((size_t)N * 2 * 4);
    float* a_dn = (float*)alloc((size_t)N * 2 * 4);
    float* xw_e = (float*)alloc((size_t)N * 128 * 4);
    float* a_se = (float*)alloc((size_t)N * 2 * 4);
    float* a_de = (float*)alloc((size_t)N * 2 * 4);
    float* hm_n = (float*)alloc((size_t)N * 64 * 4);
    float* hm_e = (float*)alloc((size_t)N * 64 * 4);
    float* Mt   = (float*)alloc((size_t)64 * 64 * 4);
    float* b0t  = (float*)alloc((size_t)64 * 4);
    int* cnt    = (int*)alloc((size_t)(N + 1) * 4);
    int* rowptr = (int*)alloc((size_t)(N + 1) * 4);
    int* cursor = (int*)alloc((size_t)(N + 1) * 4);
    int* ssrc   = (int*)alloc((size_t)E * 4);

    float* x_rec = (float*)d_out;
    float* e_rec = (float*)d_out + (size_t)N * 128;

    // CSR build (shared by both convs)
    hipMemsetAsync(cnt, 0, (size_t)N * 4, stream);
    count_kernel<<<(E + 255) / 256, 256, 0, stream>>>(dst, cnt, E);
    scan_kernel<<<1, 1024, 0, stream>>>(cnt, rowptr, N);
    hipMemcpyAsync(cursor, rowptr, (size_t)N * 4, hipMemcpyDeviceToDevice, stream);
    scatter_kernel<<<(E + 255) / 256, 256, 0, stream>>>(src, dst, cursor, ssrc, E);

    // Fold tail affine map
    fold_kernel<<<65, 64, 0, stream>>>(We, Wde, be, bde, Mt, b0t);

    // Encoders (one head per thread)
    enc_gemm<128><<<dim3((N + 255) / 256, 2), 256, 0, stream>>>(x, Wn, asn, adn, xw_n, a_sn, a_dn, N);
    enc_gemm<64><<<dim3((N + 255) / 256, 2), 256, 0, stream>>>(xe, We, ase, ade, xw_e, a_se, a_de, N);

    // Tail: 750k self-loop-only rows, folded to a single affine map
    rowmap_kernel<64><<<(NE - N + 255) / 256, 256, 0, stream>>>(xe + (size_t)N * 64, Mt, b0t,
                                                                e_rec + (size_t)N * 64, NE - N);

    // Fused message passing for both convs -> head-mean hidden states
    msg_fused<<<N, 128, 0, stream>>>(xw_n, a_sn, a_dn, xw_e, a_se, a_de, rowptr, ssrc, bn, be, hm_n, hm_e);

    // Decoders
    rowmap_kernel<128><<<(N + 255) / 256, 256, 0, stream>>>(hm_n, Wdx, bdx, x_rec, N);
    rowmap_kernel<64><<<(N + 255) / 256, 256, 0, stream>>>(hm_e, Wde, bde, e_rec, N);
}